// Round 9
// baseline (170.771 us; speedup 1.0000x reference)
//
#include <hip/hip_runtime.h>
#include <math.h>

// CRF log-likelihood, B=2048, T=80, L=128 — v9: v8 meet-in-the-middle with
// chain-split waves. Waves 0,1 run the fwd chain (each owns 64 m-states),
// waves 2,3 the bwd chain. Each chain's V is read by only 2 waves (LDS
// traffic halved vs v8). v_perm bf16 packing (1 inst), LDS stride 144
// (conflict-free phases), explicit 4-step unroll groups (renorm code
// stripped from 3 of 4 steps).
//   fwd: a_t = exp(x_t) o (E^T a_{t-1}),  a_0  = exp(start + x_0)
//   bwd: v_t = exp(x_t) o (E   v_{t+1}),  v_79 = exp(end   + x_79)
//   Z = a_39^T · E · v_40  (fwd waves: MFMA E^T·a_39, dot with bf16 v_40)

#define CRF_B 2048
#define CRF_T 80
#define CRF_L 128
#define R_REAL 4
#define VSTRIDE 144   // shorts; 288 B rows -> bank-clean b128 reads

typedef __attribute__((ext_vector_type(8))) short bf16x8_t;
typedef __attribute__((ext_vector_type(4))) float f32x4_t;

__device__ __forceinline__ int pk(float lo, float hi) {
    // packed bf16x2 = (hi & 0xFFFF0000) | (lo >> 16)  — one v_perm_b32
    return __builtin_amdgcn_perm(__float_as_int(hi), __float_as_int(lo), 0x07060302);
}
__device__ __forceinline__ unsigned short bft(float f) {
    return (unsigned short)(__float_as_uint(f) >> 16);
}
__device__ __forceinline__ float bf2f(unsigned short s) {
    return __uint_as_float(((unsigned)s) << 16);
}

__global__ __launch_bounds__(256, 2) void crf_v9_kernel(
    const float* __restrict__ x,           // [B,T,L]
    const float* __restrict__ trans,       // [L,L]
    const float* __restrict__ start_trans, // [L]
    const float* __restrict__ end_trans,   // [L]
    const int*   __restrict__ y,           // [B,T]
    float* __restrict__ out)               // [B]
{
    const int tid  = threadIdx.x;
    const int w    = tid >> 6;
    const int lane = tid & 63;
    const int quad = lane >> 4;
    const int n16  = lane & 15;            // tile row; real row = row0 + (n16&3)
    const int row0 = blockIdx.x * R_REAL;
    const int brow = row0 + (n16 & (R_REAL - 1));

    const bool isF  = (w < 2);             // waves 0,1: fwd ; waves 2,3: bwd
    const int  half = w & 1;               // which 64-state half this wave owns
    const int  mb   = 64 * half;           // m-state base

    __shared__ __attribute__((aligned(16))) short VbF[2][16][VSTRIDE];
    __shared__ __attribute__((aligned(16))) short VbB[2][16][VSTRIDE];
    __shared__ __attribute__((aligned(16))) float maxb[2][16][2]; // [chain][row][half]
    __shared__ __attribute__((aligned(16))) float sumb[16][2];
    __shared__ float cb[16];               // crunB handoff (bwd -> writer)
    __shared__ float numb[R_REAL];

    // ---------------- numerator: wave w -> real row row0+w ----------------
    {
        const int bb = row0 + w;
        const int* yb = y + bb * CRF_T;
        const float* xbn = x + (size_t)bb * CRF_T * CRF_L;
        float p = 0.f;
        for (int t = lane; t < CRF_T; t += 64) {
            const int yt = yb[t];
            p += xbn[t * CRF_L + yt];
            p += (t + 1 < CRF_T) ? trans[yt * CRF_L + yb[t + 1]] : end_trans[yt];
            if (t == 0) p += start_trans[yt];
        }
        #pragma unroll
        for (int off = 1; off <= 32; off <<= 1) p += __shfl_xor(p, off);
        if (lane == 0) numb[w] = p;
    }

    // ------------- A-frags: 4 m-tiles of one direction (64 VGPR) -------------
    // A[m][k]: lane(q,n16) holds m = mb + 16mt + n16, k = 32kk + 8q + j.
    bf16x8_t Af[4][4];
    #pragma unroll
    for (int mt = 0; mt < 4; ++mt) {
        const int m = mb + 16 * mt + n16;
        #pragma unroll
        for (int kk = 0; kk < 4; ++kk) {
            union { bf16x8_t v; unsigned short s[8]; } u;
            #pragma unroll
            for (int j = 0; j < 8; ++j) {
                const int k = 32 * kk + 8 * quad + j;
                u.s[j] = bft(__expf(isF ? trans[k * CRF_L + m]
                                        : trans[m * CRF_L + k]));
            }
            Af[mt][kk] = u.v;
        }
    }

    const float* xr = x + (size_t)brow * CRF_T * CRF_L;
    const int ci = isF ? 0 : 1;            // chain index for maxb
    short (*Vw)[16][VSTRIDE] = isF ? VbF : VbB;

    // time index for pair-step k: fwd t = k, bwd t = 79 - k
    f32x4_t P[4];
    float invM = 1.f, crun = 0.f;

    // ---------------- init: a_0 / v_79 into buffer 0 ----------------
    {
        const int t0 = isF ? 0 : 79;
        const float* bt = isF ? start_trans : end_trans;
        #pragma unroll
        for (int mt = 0; mt < 4; ++mt) {
            const int sc = mb + 16 * mt + 4 * quad;
            const f32x4_t b4 = *(const f32x4_t*)&bt[sc];
            const f32x4_t x4 = *(const f32x4_t*)&xr[t0 * CRF_L + sc];
            #pragma unroll
            for (int r = 0; r < 4; ++r)
                P[mt][r] = __expf(b4[r] + x4[r]);
        }
        short* dst = &Vw[0][n16][0];
        #pragma unroll
        for (int mt = 0; mt < 4; ++mt) {
            const int sc = mb + 16 * mt + 4 * quad;
            *(int2*)&dst[sc] = make_int2(pk(P[mt][0], P[mt][1]),
                                         pk(P[mt][2], P[mt][3]));
        }
        __syncthreads();
    }

    // current emissions for k=1
    f32x4_t xc[4], xn[4];
    {
        const int t1 = isF ? 1 : 78;
        #pragma unroll
        for (int mt = 0; mt < 4; ++mt)
            xc[mt] = *(const f32x4_t*)&xr[t1 * CRF_L + mb + 16 * mt + 4 * quad];
    }

    auto step = [&](int k, const bool AP, const bool MX, const bool PRE) {
        if (PRE) {
            const int tn = isF ? (k + 1) : (78 - k);
            #pragma unroll
            for (int mt = 0; mt < 4; ++mt)
                xn[mt] = *(const f32x4_t*)&xr[tn * CRF_L + mb + 16 * mt + 4 * quad];
        }
        if (AP) {
            const float2 mv = *(const float2*)&maxb[ci][n16][0];
            const float M = fmaxf(mv.x, mv.y);
            crun += __logf(M);
            invM  = __builtin_amdgcn_rcpf(M);
        }
        // exp first — transcendental overlaps the MFMA chain
        float e[4][4];
        #pragma unroll
        for (int mt = 0; mt < 4; ++mt)
        #pragma unroll
        for (int r = 0; r < 4; ++r) {
            float ev = __expf(xc[mt][r]);
            if (AP) ev *= invM;
            e[mt][r] = ev;
        }
        // B-frags: full previous V of this chain
        const short* vrow = &Vw[(k - 1) & 1][n16][0];
        bf16x8_t Bf[4];
        #pragma unroll
        for (int kk = 0; kk < 4; ++kk)
            Bf[kk] = *(const bf16x8_t*)&vrow[32 * kk + 8 * quad];
        #pragma unroll
        for (int mt = 0; mt < 4; ++mt) {
            f32x4_t a = {0.f, 0.f, 0.f, 0.f};
            #pragma unroll
            for (int kk = 0; kk < 4; ++kk)
                a = __builtin_amdgcn_mfma_f32_16x16x32_bf16(Af[mt][kk], Bf[kk], a, 0, 0, 0);
            #pragma unroll
            for (int r = 0; r < 4; ++r)
                P[mt][r] = a[r] * e[mt][r];
        }
        if (MX) {
            float g = P[0][0];
            #pragma unroll
            for (int mt = 0; mt < 4; ++mt)
            #pragma unroll
            for (int r = 0; r < 4; ++r)
                g = fmaxf(g, P[mt][r]);
            g = fmaxf(g, __shfl_xor(g, 16));
            g = fmaxf(g, __shfl_xor(g, 32));
            if (lane < 16) maxb[ci][n16][half] = g;   // this wave's 64-state max
        }
        // write V_t to the other buffer (always — k=39 feeds the combine)
        short* dst = &Vw[k & 1][n16][0];
        #pragma unroll
        for (int mt = 0; mt < 4; ++mt) {
            const int sc = mb + 16 * mt + 4 * quad;
            *(int2*)&dst[sc] = make_int2(pk(P[mt][0], P[mt][1]),
                                         pk(P[mt][2], P[mt][3]));
        }
        __syncthreads();
        #pragma unroll
        for (int mt = 0; mt < 4; ++mt) xc[mt] = xn[mt];
    };

    // ---------------- pair-steps 1..39, 4-step groups ----------------
    step(1, false, false, true);
    step(2, false, false, true);
    step(3, false, true,  true);
    for (int g = 1; g <= 8; ++g) {
        const int k = 4 * g;
        step(k,     true,  false, true);
        step(k + 1, false, false, true);
        step(k + 2, false, false, true);
        step(k + 3, false, true,  true);
    }
    step(36, true,  false, true);
    step(37, false, false, true);
    step(38, false, false, true);
    step(39, false, false, false);

    // ---------------- combine: fwd waves compute (E^T a39) · v40 ----------------
    if (isF) {
        const short* vrow = &VbF[1][n16][0];    // a_39 (bf16)
        bf16x8_t Bf[4];
        #pragma unroll
        for (int kk = 0; kk < 4; ++kk)
            Bf[kk] = *(const bf16x8_t*)&vrow[32 * kk + 8 * quad];
        float sv = 0.f;
        #pragma unroll
        for (int mt = 0; mt < 4; ++mt) {
            f32x4_t a = {0.f, 0.f, 0.f, 0.f};
            #pragma unroll
            for (int kk = 0; kk < 4; ++kk)
                a = __builtin_amdgcn_mfma_f32_16x16x32_bf16(Af[mt][kk], Bf[kk], a, 0, 0, 0);
            const int sc = mb + 16 * mt + 4 * quad;
            const int2 v2 = *(const int2*)&VbB[1][n16][sc];   // v_40 (bf16)
            sv += a[0] * bf2f((unsigned short)(v2.x & 0xFFFF));
            sv += a[1] * bf2f((unsigned short)(((unsigned)v2.x) >> 16));
            sv += a[2] * bf2f((unsigned short)(v2.y & 0xFFFF));
            sv += a[3] * bf2f((unsigned short)(((unsigned)v2.y) >> 16));
        }
        sv += __shfl_xor(sv, 16);
        sv += __shfl_xor(sv, 32);
        if (lane < 16) sumb[n16][half] = sv;
    } else {
        if (w == 2 && lane < 16) cb[n16] = crun;   // crunB per row
    }
    __syncthreads();
    if (tid < R_REAL) {
        const float2 sb = *(const float2*)&sumb[tid][0];
        const float S = sb.x + sb.y;
        out[row0 + tid] = numb[tid] - (crun + cb[tid] + __logf(S));  // crun = crunF (wave 0)
    }
}

extern "C" void kernel_launch(void* const* d_in, const int* in_sizes, int n_in,
                              void* d_out, int out_size, void* d_ws, size_t ws_size,
                              hipStream_t stream) {
    const float* x     = (const float*)d_in[0];
    const float* trans = (const float*)d_in[1];
    const float* st    = (const float*)d_in[2];
    const float* et    = (const float*)d_in[3];
    const int*   y     = (const int*)d_in[4];
    float* out = (float*)d_out;

    crf_v9_kernel<<<CRF_B / R_REAL, 256, 0, stream>>>(x, trans, st, et, y, out);
}